// Round 6
// baseline (120.564 us; speedup 1.0000x reference)
//
#include <hip/hip_runtime.h>

// DynamicGaussianBlur: [B=4, D=160, H=160, W=160, C=2] fp32, sigma [4,3],
// separable 3D gaussian, window 13 (radius 6), SAME zero padding.
// Two passes, channel-interleaved float2 throughout:
//   A: D-blur, LDS-staged (d,w) slab at fixed (b,h): 32x160 f2 slab,
//      column-walk along d, store from registers.       in -> ws
//   B: fused H+W blur per (b,d,h-tile): 32x160 f2 slab, H-blur column walk,
//      re-lay as padded hbuf in same LDS, W-blur, store. ws -> out
//      (unchanged from round 5 — measured ~40 us)

#define WSZ 13
#define RAD 6

constexpr int BB = 4, DD = 160, HH = 160, WW = 160;
constexpr int R2 = 160;             // row in float2
constexpr int P2 = HH * WW;         // plane in float2 (25,600)
constexpr int N2 = DD * P2;         // batch in float2
constexpr int R4 = 80;              // row in float4
constexpr int P4 = P2 / 2;          // plane in float4 (12,800)
constexpr int N4 = N2 / 2;

#define TB 20                        // output rows per block (both passes)
#define SLABR (TB + 12)              // 32 slab rows
#define HBS 172                      // pass-B hbuf row stride

__device__ __forceinline__ void make_weights(float sig, float* w) {
    const float invd = 1.0f / (2.0f * sig * sig + 1e-7f);
    float s = 0.0f;
#pragma unroll
    for (int k = 0; k < WSZ; ++k) {
        const float loc = (float)(k - RAD);
        w[k] = __expf(-loc * loc * invd);
        s += w[k];
    }
    const float inv = 1.0f / s;
#pragma unroll
    for (int k = 0; k < WSZ; ++k) w[k] *= inv;
}

// ---------------- Pass A: D-blur, LDS-staged (d,w) slab at fixed (b,h) ----------------
__global__ __launch_bounds__(320) void blur_d_slab(const float2* __restrict__ in,
                                                   float2* __restrict__ ws,
                                                   const float* __restrict__ sigma) {
    __shared__ __align__(16) float2 lds[SLABR * R2];   // 40,960 B

    const int tid  = threadIdx.x;
    const int bx   = blockIdx.x;
    const int h    = bx % HH;                // fastest: adjacent blocks stream adjacent rows
    const int tile = (bx / HH) & 7;          // 8 d-tiles of 20
    const int b    = bx / (8 * HH);
    const int d0   = tile * TB;

    float wd[WSZ];
    make_weights(sigma[b * 3 + 0], wd);

    // ---- stage slab: rows d0-6 .. d0+25 (32 x 160 f2) as float4, 8/thread ----
    const float4* in4 = (const float4*)in;
    float4* l4 = (float4*)lds;
#pragma unroll
    for (int j = 0; j < 8; ++j) {
        const int f = j * 320 + tid;                   // 0..2559
        const int r = f / R4, q = f % R4;
        const int d = d0 - 6 + r;
        float4 v = make_float4(0.f, 0.f, 0.f, 0.f);
        if (d >= 0 && d < DD) v = in4[b * N4 + d * P4 + h * R4 + q];
        l4[f] = v;
    }
    __syncthreads();

    // ---- column walk along d; store straight to ws (coalesced, lanes across w) ----
    const int w  = tid % 160;
    const int r0 = (tid / 160) * 10;                   // 2 segments of 10 rows
    float2* ocol = ws + b * N2 + h * R2 + w;

    float2 win[WSZ];
#pragma unroll
    for (int k = 0; k < WSZ - 1; ++k) win[k] = lds[(r0 + k) * R2 + w];
#pragma unroll
    for (int i = 0; i < 10; ++i) {
        win[WSZ - 1] = lds[(r0 + i + WSZ - 1) * R2 + w];
        float ax = 0.0f, ay = 0.0f;
#pragma unroll
        for (int k = 0; k < WSZ; ++k) { ax += wd[k] * win[k].x; ay += wd[k] * win[k].y; }
        ocol[(d0 + r0 + i) * P2] = make_float2(ax, ay);
#pragma unroll
        for (int k = 0; k < WSZ - 1; ++k) win[k] = win[k + 1];
    }
}

// ---------------- Pass B: fused H+W blur, one (b,d,h-tile) per block ----------------
__global__ __launch_bounds__(320) void blur_hw(const float2* __restrict__ ws,
                                               float2* __restrict__ out,
                                               const float* __restrict__ sigma) {
    __shared__ __align__(16) float2 lds[SLABR * R2];   // 40,960 B

    const int tid  = threadIdx.x;
    const int bx   = blockIdx.x;
    const int tile = bx & 7;                 // 8 h-tiles of 20 rows
    const int d    = (bx >> 3) % DD;
    const int b    = bx / (8 * DD);
    const int h0   = tile * TB;

    float wh[WSZ];
    make_weights(sigma[b * 3 + 1], wh);

    const float2* plane = ws + b * N2 + d * P2;

    // ---- load slab rows h0-6 .. h0+25 (32 x 160 f2) as float4: 8/thread ----
    const float4* p4 = (const float4*)plane;
    float4* l4 = (float4*)lds;
#pragma unroll
    for (int j = 0; j < 8; ++j) {
        const int f = j * 320 + tid;
        const int r = f / R4, q = f % R4;
        const int hh = h0 - 6 + r;
        float4 v = make_float4(0.f, 0.f, 0.f, 0.f);
        if (hh >= 0 && hh < HH) v = p4[hh * R4 + q];
        l4[f] = v;
    }
    __syncthreads();

    // ---- H-blur: one column-walk per thread ----
    float2 o[10];
    {
        const int w  = tid % 160;
        const int r0 = (tid / 160) * 10;
        float2 win[WSZ];
#pragma unroll
        for (int k = 0; k < WSZ - 1; ++k) win[k] = lds[(r0 + k) * R2 + w];
#pragma unroll
        for (int i = 0; i < 10; ++i) {
            win[WSZ - 1] = lds[(r0 + i + WSZ - 1) * R2 + w];
            float ax = 0.0f, ay = 0.0f;
#pragma unroll
            for (int k = 0; k < WSZ; ++k) { ax += wh[k] * win[k].x; ay += wh[k] * win[k].y; }
            o[i] = make_float2(ax, ay);
#pragma unroll
            for (int k = 0; k < WSZ - 1; ++k) win[k] = win[k + 1];
        }
    }
    __syncthreads();   // all slab reads done; reuse LDS as hbuf[20][172]

    // ---- write hbuf: zero stripes + data shifted +6 ----
    float2* hb = lds;
    if (tid < 240) {
        const int r = tid / 12, c = tid % 12;
        const int col = (c < 6) ? c : (160 + c);
        hb[r * HBS + col] = make_float2(0.0f, 0.0f);
    }
    {
        const int w  = tid % 160;
        const int r0 = (tid / 160) * 10;
#pragma unroll
        for (int i = 0; i < 10; ++i) hb[(r0 + i) * HBS + 6 + w] = o[i];
    }
    __syncthreads();

    // ---- W-blur: 3200 outputs, coalesced stores ----
    float ww[WSZ];
    make_weights(sigma[b * 3 + 2], ww);

    float2* oplane = out + b * N2 + d * P2 + h0 * R2;
#pragma unroll
    for (int j = 0; j < 10; ++j) {
        const int oidx = j * 320 + tid;
        const int r = oidx / 160, w = oidx % 160;
        const float2* src = &hb[r * HBS + w];
        float ax = 0.0f, ay = 0.0f;
#pragma unroll
        for (int k = 0; k < WSZ; ++k) { const float2 v = src[k]; ax += ww[k] * v.x; ay += ww[k] * v.y; }
        oplane[oidx] = make_float2(ax, ay);
    }
}

extern "C" void kernel_launch(void* const* d_in, const int* in_sizes, int n_in,
                              void* d_out, int out_size, void* d_ws, size_t ws_size,
                              hipStream_t stream) {
    const float2* img   = (const float2*)d_in[0];
    const float*  sigma = (const float*)d_in[1];
    float2* out = (float2*)d_out;
    float2* ws  = (float2*)d_ws;

    blur_d_slab<<<dim3(BB * 8 * HH), dim3(320), 0, stream>>>(img, ws, sigma);
    blur_hw<<<dim3(BB * DD * 8), dim3(320), 0, stream>>>(ws, out, sigma);
}